// Round 11
// baseline (628.569 us; speedup 1.0000x reference)
//
#include <hip/hip_runtime.h>

// Problem constants (fixed by the reference)
#define T_SEQ   4096
#define BATCH   32
#define DIM     512
#define MROWS   (T_SEQ * BATCH)          // 131072 GEMM rows
#define S_STRIDE (BATCH * DIM)           // 16384 elements per time step
#define OUT_ELEMS ((size_t)T_SEQ * BATCH * DIM)   // 67108864
#define NCH     32                        // T-chunks for parallel scan
#define CLEN    (T_SEQ / NCH)             // 128 steps per chunk
#define NCHAIN  (BATCH * DIM)             // 16384 independent chains

// B-stationary GEMM geometry
#define CHROWS  32                        // A-rows per chunk
#define NCHUNK  16                        // 512 rows per block
#define LDSB    98304                     // 3 x 32 KB A buffers

typedef __bf16 bf8_t __attribute__((ext_vector_type(8)));
typedef float  f4_t  __attribute__((ext_vector_type(4)));
typedef unsigned short u16x8 __attribute__((ext_vector_type(8)));
typedef __attribute__((address_space(1))) void gvoid_t;
typedef __attribute__((address_space(3))) void lvoid_t;

__device__ __forceinline__ unsigned short f2bf(float f) {
    unsigned int u = __float_as_uint(f);
    u += 0x7FFFu + ((u >> 16) & 1u);     // round-to-nearest-even
    return (unsigned short)(u >> 16);
}
__device__ __forceinline__ float bf2f(unsigned short b) {
    return __uint_as_float(((unsigned int)b) << 16);
}

#define VMCn(n) asm volatile("s_waitcnt vmcnt(" #n ")" ::: "memory")
#define LGKM0   asm volatile("s_waitcnt lgkmcnt(0)" ::: "memory")

// ---------------- B-stationary bf16 GEMM  C = A * B^T ----------------
// Block = 256 thr / 4 waves, 1 wave/SIMD (launch_bounds(256,1): 512-VGPR
// budget). Each wave holds B for its 64 cols x K=512 ENTIRELY in registers
// (bq[4][16] = 256 VGPR, static indices only), converted from f32 W in the
// prologue. Grid 512 = 256 M-groups x 2 N-halves; pair (d, d+8) -> same XCD
// so A is HBM-read once, pair-read hits L2. Per block: 16 chunks of 32 A
// rows; chunk = stage A (8 gll/wave or reg-cvt) + 32 ds_read + 128 MFMA +
// C-write + counted vmcnt (FIFO retires previous chunk's stage only) +
// one barrier. No B staging, no B reads in the loop.
// LDS swizzle (R6-proven, 0 conflicts): 16B slot sl of row r at sl^(r&7);
// gll sources pre-inverse-swizzled (wave-uniform XOR since r&7 == j).
// AF32=1: A f32 -> P[16] regs -> cvt -> swizzled ds_write (bit-identical).
template <int AF32>
__global__ __launch_bounds__(256, 1)
void k_gemm_bs(const void* __restrict__ Ap,
               const float* __restrict__ Bf,
               unsigned short* __restrict__ C) {
    extern __shared__ unsigned short lds[];   // 3 x 16384 shorts

    const int tid  = threadIdx.x;
    const int lane = tid & 63;
    const int wv   = tid >> 6;          // wave 0..3
    const int l15  = lane & 15;
    const int l16  = lane >> 4;         // 0..3 (k-slot)

    // grid: pair p on one XCD via (d, d+8)
    const int d  = blockIdx.x;
    const int p  = (d >> 4) * 8 + (d & 7);   // M-group 0..255
    const int nh = (d >> 3) & 1;             // N-half
    const size_t gm = (size_t)p * 512;
    const int    nb = nh * 256 + wv * 64;    // wave's col base

    // ---- B panel -> registers: 64 frags = 256 VGPR, cvt from f32 ----
    bf8_t bq[4][16];
#pragma unroll
    for (int n = 0; n < 4; ++n)
#pragma unroll
        for (int k = 0; k < 16; ++k) {
            const float* bp = Bf + (size_t)(nb + n * 16 + l15) * 512 + k * 32 + l16 * 8;
            float4 f0 = *reinterpret_cast<const float4*>(bp);
            float4 f1 = *reinterpret_cast<const float4*>(bp + 4);
            u16x8 o;
            o[0] = f2bf(f0.x); o[1] = f2bf(f0.y); o[2] = f2bf(f0.z); o[3] = f2bf(f0.w);
            o[4] = f2bf(f1.x); o[5] = f2bf(f1.y); o[6] = f2bf(f1.z); o[7] = f2bf(f1.w);
            bq[n][k] = *reinterpret_cast<bf8_t*>(&o);
        }

    const unsigned short* Ab = (const unsigned short*)Ap;
    const float*          Af = (const float*)Ap;

    unsigned short* b0 = lds;
    unsigned short* b1 = lds + 16384;
    unsigned short* b2 = lds + 32768;

    // ---- bf16 A stage: 8 gll per wave, one row each (r&7 == j) ----
    auto stage = [&](unsigned short* buf, int c) {
#pragma unroll
        for (int j = 0; j < 8; ++j) {
            const int r = wv * 8 + j;
            const unsigned short* src =
                Ab + (gm + c * CHROWS + r) * 512 + ((lane ^ j) * 8);
            __builtin_amdgcn_global_load_lds((gvoid_t*)src,
                (lvoid_t*)&buf[r * 512], 16, 0, 0);
        }
    };
    // ---- f32 A reg-stage: thread -> row tid/8, 64-float span ----
    const int rr = tid >> 3, sg = tid & 7;
    float4 P[16];
    auto loadP = [&](int c) {
        const float* src = Af + (gm + c * CHROWS + rr) * 512 + sg * 64;
#pragma unroll
        for (int q = 0; q < 16; ++q)
            P[q] = *reinterpret_cast<const float4*>(src + q * 4);
    };
    auto writeP = [&](unsigned short* buf) {
#pragma unroll
        for (int i = 0; i < 8; ++i) {
            u16x8 o;
            o[0] = f2bf(P[2*i].x);   o[1] = f2bf(P[2*i].y);
            o[2] = f2bf(P[2*i].z);   o[3] = f2bf(P[2*i].w);
            o[4] = f2bf(P[2*i+1].x); o[5] = f2bf(P[2*i+1].y);
            o[6] = f2bf(P[2*i+1].z); o[7] = f2bf(P[2*i+1].w);
            const int s = sg * 8 + i;
            *reinterpret_cast<u16x8*>(&buf[rr * 512 + ((s ^ (rr & 7)) * 8)]) = o;
        }
    };

    // ---- prologue ----
    if constexpr (AF32) {
        loadP(0); VMCn(0); writeP(b0); LGKM0;
        loadP(1);
    } else {
        stage(b0, 0); stage(b1, 1);
        VMCn(8);                         // chunk 0 landed; chunk 1 in flight
    }
    __builtin_amdgcn_s_barrier();

    // ---- main loop: 16 chunks ----
    for (int c = 0; c < NCHUNK; ++c) {
        if constexpr (!AF32) {
            if (c + 2 < NCHUNK) stage(b2, c + 2);
        }

        // compute chunk c from b0: 32 ds_read_b128 + 128 MFMA
        f4_t acc[2][4] = {};
#pragma unroll
        for (int k = 0; k < 16; ++k) {
            const int so = ((k * 4 + l16) ^ (l15 & 7)) * 8;
            bf8_t a0 = *reinterpret_cast<const bf8_t*>(&b0[l15 * 512 + so]);
            bf8_t a1 = *reinterpret_cast<const bf8_t*>(&b0[(16 + l15) * 512 + so]);
#pragma unroll
            for (int n = 0; n < 4; ++n) {
                acc[0][n] = __builtin_amdgcn_mfma_f32_16x16x32_bf16(a0, bq[n][k], acc[0][n], 0, 0, 0);
                acc[1][n] = __builtin_amdgcn_mfma_f32_16x16x32_bf16(a1, bq[n][k], acc[1][n], 0, 0, 0);
            }
        }

        // C-write (C/D layout: col=lane&15, row=(lane>>4)*4+reg)
#pragma unroll
        for (int m = 0; m < 2; ++m)
#pragma unroll
            for (int n = 0; n < 4; ++n) {
                const size_t row0 = gm + c * CHROWS + m * 16 + l16 * 4;
                const int    col  = nb + n * 16 + l15;
#pragma unroll
                for (int r = 0; r < 4; ++r)
                    C[(row0 + r) * 512 + col] = f2bf(acc[m][n][r]);
            }

        // waits + publish + rotate
        if constexpr (AF32) {
            if (c + 1 < NCHUNK) {
                VMCn(32);                // newest 32 = this chunk's stores ->
                writeP(b1);              // loads(c+1) retired; write them
                LGKM0;
                if (c + 2 < NCHUNK) loadP(c + 2);
                __builtin_amdgcn_s_barrier();
            }
            { unsigned short* t = b0; b0 = b1; b1 = t; }
        } else {
            if (c + 2 < NCHUNK)      { VMCn(40); }   // retire gll(c+1), keep gll(c+2)+stores
            else if (c + 1 < NCHUNK) { VMCn(32); }   // retire gll(c+1), keep stores
            if (c + 1 < NCHUNK) __builtin_amdgcn_s_barrier();
            { unsigned short* t = b0; b0 = b1; b1 = b2; b2 = t; }
        }
    }
}

// ------------- chunk-parallel scan, pass 1: per-chunk (A,B) summaries -------
__global__ __launch_bounds__(256)
void k_scan_p1(const unsigned short* __restrict__ q,
               const float* __restrict__ w_hh,
               const float* __restrict__ b_ih,
               float* __restrict__ Asum,
               float* __restrict__ Bsum) {
    const int g = (blockIdx.x & 63) * 256 + threadIdx.x;
    const int c = blockIdx.x >> 6;
    const float w  = w_hh[g & 511];
    const float bs = b_ih[g & 511];
    const unsigned short* p = q + (size_t)c * CLEN * S_STRIDE + g;

    float A = 0.f, Bv = 0.f;
    float s0[8], s1[8];
#pragma unroll
    for (int j = 0; j < 8; ++j) s0[j] = bf2f(p[(size_t)j * S_STRIDE]);
#pragma unroll
    for (int j = 0; j < 8; ++j) s1[j] = bf2f(p[(size_t)(8 + j) * S_STRIDE]);

    for (int j0 = 0; j0 < CLEN; j0 += 16) {
#pragma unroll
        for (int j = 0; j < 8; ++j) {
            float qv = s0[j] + bs;
            A  = fmaxf(fmaf(w, A, qv), 0.f);
            Bv = fmaf(w, Bv, qv);
        }
        if (j0 + 16 < CLEN) {
#pragma unroll
            for (int j = 0; j < 8; ++j) s0[j] = bf2f(p[(size_t)(j0 + 16 + j) * S_STRIDE]);
        }
#pragma unroll
        for (int j = 0; j < 8; ++j) {
            float qv = s1[j] + bs;
            A  = fmaxf(fmaf(w, A, qv), 0.f);
            Bv = fmaf(w, Bv, qv);
        }
        if (j0 + 24 < CLEN) {
#pragma unroll
            for (int j = 0; j < 8; ++j) s1[j] = bf2f(p[(size_t)(j0 + 24 + j) * S_STRIDE]);
        }
    }
    Asum[(size_t)c * NCHAIN + g] = A;
    Bsum[(size_t)c * NCHAIN + g] = Bv;
}

// ------------- pass 2: per-block stitch + exact replay ----------------------
template <int MODE>
__global__ __launch_bounds__(256)
void k_scan_p2(const unsigned short* __restrict__ q,
               const float* __restrict__ w_hh,
               const float* __restrict__ b_ih,
               const float* __restrict__ Asum,
               const float* __restrict__ Bsum,
               float* __restrict__ of32,
               unsigned short* __restrict__ ob16,
               float* __restrict__ hT) {
    const int g = (blockIdx.x & 63) * 256 + threadIdx.x;
    const int c = blockIdx.x >> 6;
    const float w  = w_hh[g & 511];
    const float bs = b_ih[g & 511];

    float cw = w;
#pragma unroll
    for (int i = 0; i < 7; ++i) cw *= cw;      // w^128
    float h = 0.f;
    for (int cc = 0; cc < c; ++cc)
        h = fmaxf(Asum[(size_t)cc * NCHAIN + g], fmaf(cw, h, Bsum[(size_t)cc * NCHAIN + g]));

    const size_t base = (size_t)c * CLEN * S_STRIDE + g;
    const unsigned short* p = q + base;

    float s0[8], s1[8];
#pragma unroll
    for (int j = 0; j < 8; ++j) s0[j] = bf2f(p[(size_t)j * S_STRIDE]);
#pragma unroll
    for (int j = 0; j < 8; ++j) s1[j] = bf2f(p[(size_t)(8 + j) * S_STRIDE]);

    for (int j0 = 0; j0 < CLEN; j0 += 16) {
#pragma unroll
        for (int j = 0; j < 8; ++j) {
            h = fmaxf(fmaf(w, h, s0[j] + bs), 0.f);
            const size_t idx = base + (size_t)(j0 + j) * S_STRIDE;
            if (MODE == 0) of32[idx] = h; else ob16[idx] = f2bf(h);
        }
        if (j0 + 16 < CLEN) {
#pragma unroll
            for (int j = 0; j < 8; ++j) s0[j] = bf2f(p[(size_t)(j0 + 16 + j) * S_STRIDE]);
        }
#pragma unroll
        for (int j = 0; j < 8; ++j) {
            h = fmaxf(fmaf(w, h, s1[j] + bs), 0.f);
            const size_t idx = base + (size_t)(j0 + 8 + j) * S_STRIDE;
            if (MODE == 0) of32[idx] = h; else ob16[idx] = f2bf(h);
        }
        if (j0 + 24 < CLEN) {
#pragma unroll
            for (int j = 0; j < 8; ++j) s1[j] = bf2f(p[(size_t)(j0 + 24 + j) * S_STRIDE]);
        }
    }
    if (c == NCH - 1) hT[g] = h;
}

extern "C" void kernel_launch(void* const* d_in, const int* in_sizes, int n_in,
                              void* d_out, int out_size, void* d_ws, size_t ws_size,
                              hipStream_t stream) {
    const float* x    = (const float*)d_in[0];   // (4096,32,512)
    const float* W_ih = (const float*)d_in[1];   // (2,512,512)
    const float* w_hh = (const float*)d_in[2];   // (2,512)
    const float* b_ih = (const float*)d_in[3];   // (2,512)

    // 96 KB dynamic LDS opt-in (idempotent; outside stream ops)
    hipFuncSetAttribute(reinterpret_cast<const void*>(&k_gemm_bs<1>),
                        hipFuncAttributeMaxDynamicSharedMemorySize, LDSB);
    hipFuncSetAttribute(reinterpret_cast<const void*>(&k_gemm_bs<0>),
                        hipFuncAttributeMaxDynamicSharedMemorySize, LDSB);

    // ---- workspace layout (~138 MB) ----
    unsigned short* proj2 = (unsigned short*)d_ws;                // 134 MB
    float* Asum = (float*)(proj2 + OUT_ELEMS);                    // 2 MB
    float* Bsum = Asum + (size_t)NCH * NCHAIN;                    // 2 MB

    // ---- d_out staging: proj1 (bf16) lower half, ys1 (bf16) upper half ----
    unsigned short* proj1 = (unsigned short*)d_out;
    unsigned short* ys1   = proj1 + OUT_ELEMS;
    float* out = (float*)d_out;
    float* hT  = out + OUT_ELEMS;                                 // h_n (2,32,512)

    const int sgrid = 64 * NCH;             // 2048 blocks for scan passes

    // 1. layer-0 GEMM (A = x f32 fused cvt, B = W0 f32 in-reg cvt) -> proj1
    k_gemm_bs<1><<<512, 256, LDSB, stream>>>(x, W_ih, proj1);
    // 2-3. layer-0 chunked scan -> ys1 (bf16) + hT0
    k_scan_p1<<<sgrid, 256, 0, stream>>>(proj1, w_hh, b_ih, Asum, Bsum);
    k_scan_p2<1><<<sgrid, 256, 0, stream>>>(proj1, w_hh, b_ih, Asum, Bsum,
                                            nullptr, ys1, hT);
    // 4. layer-1 GEMM (A = ys1 bf16, B = W1 f32 in-reg cvt) -> proj2 (ws)
    k_gemm_bs<0><<<512, 256, LDSB, stream>>>(ys1, W_ih + 512 * 512, proj2);
    // 5-6. layer-1 chunked scan -> final out (f32, overwrites proj1/ys1) + hT1
    k_scan_p1<<<sgrid, 256, 0, stream>>>(proj2, w_hh + DIM, b_ih + DIM, Asum, Bsum);
    k_scan_p2<0><<<sgrid, 256, 0, stream>>>(proj2, w_hh + DIM, b_ih + DIM, Asum, Bsum,
                                            out, nullptr, hT + NCHAIN);
}

// Round 12
// 627.787 us; speedup vs baseline: 1.0012x; 1.0012x over previous
//
#include <hip/hip_runtime.h>

// Problem constants (fixed by the reference)
#define T_SEQ   4096
#define BATCH   32
#define DIM     512
#define MROWS   (T_SEQ * BATCH)          // 131072 GEMM rows
#define S_STRIDE (BATCH * DIM)           // 16384 elements per time step
#define OUT_ELEMS ((size_t)T_SEQ * BATCH * DIM)   // 67108864
#define NCH     32                        // T-chunks for parallel scan
#define CLEN    (T_SEQ / NCH)             // 128 steps per chunk
#define NCHAIN  (BATCH * DIM)             // 16384 independent chains

// 8-phase GEMM geometry: BM=BN=256, BK=64, 8 waves (2Mx4N), LDS 128 KB
// persistent: 256 blocks x 4 M-tile jobs, spliced prologues
#define OFF_A0  0          // shorts; each region 16384 shorts = 32 KB
#define OFF_A1  16384
#define OFF_B0  32768
#define OFF_B1  49152
#define GLDS_B  131072

typedef __bf16 bf8_t __attribute__((ext_vector_type(8)));
typedef float  f4_t  __attribute__((ext_vector_type(4)));
typedef unsigned short u16x8 __attribute__((ext_vector_type(8)));
typedef __attribute__((address_space(1))) void gvoid_t;
typedef __attribute__((address_space(3))) void lvoid_t;

__device__ __forceinline__ unsigned short f2bf(float f) {
    unsigned int u = __float_as_uint(f);
    u += 0x7FFFu + ((u >> 16) & 1u);     // round-to-nearest-even
    return (unsigned short)(u >> 16);
}
__device__ __forceinline__ float bf2f(unsigned short b) {
    return __uint_as_float(((unsigned int)b) << 16);
}

#define VMC(n)  asm volatile("s_waitcnt vmcnt(" #n ")" ::: "memory")
#define LGKM0   asm volatile("s_waitcnt lgkmcnt(0)" ::: "memory")
#define PH_PRE()  do { __builtin_amdgcn_s_barrier(); LGKM0;                    \
                       __builtin_amdgcn_sched_barrier(0);                      \
                       __builtin_amdgcn_s_setprio(1); } while (0)
#define PH_POST() do { __builtin_amdgcn_s_setprio(0);                          \
                       __builtin_amdgcn_sched_barrier(0);                      \
                       __builtin_amdgcn_s_barrier(); } while (0)

// ---------------- f32 -> bf16 convert (weights only) -----------------
__global__ __launch_bounds__(256) void k_cvt(const float* __restrict__ in,
                                             unsigned short* __restrict__ out) {
    size_t i = ((size_t)blockIdx.x * 256 + threadIdx.x) * 8;
    float4 a = *reinterpret_cast<const float4*>(in + i);
    float4 b = *reinterpret_cast<const float4*>(in + i + 4);
    u16x8 o;
    o[0] = f2bf(a.x); o[1] = f2bf(a.y); o[2] = f2bf(a.z); o[3] = f2bf(a.w);
    o[4] = f2bf(b.x); o[5] = f2bf(b.y); o[6] = f2bf(b.z); o[7] = f2bf(b.w);
    *reinterpret_cast<u16x8*>(out + i) = o;
}

// ---------------- persistent 8-phase 256x256 bf16 GEMM  C = A * B^T ---
// 256 blocks (1/CU); block = (N-half nh, M-group mg) does 4 M-tile jobs
// back-to-back. Job = 4 iters x 8 phases (R6-verified schedule); at i=3
// the st2 stage slots splice the NEXT job's kt0/kt1 tiles -> one continuous
// pipeline, single prologue. vmcnt counts identical to R6 steady state.
// XCD pairing: blocks b and b+128 (same b&7 -> same XCD) share A-panels.
template <int AF32>
__global__ __launch_bounds__(512, 1)
void k_gemm8p(const void* __restrict__ Ap,
              const unsigned short* __restrict__ Bp,
              unsigned short* __restrict__ C) {
    extern __shared__ unsigned short lds[];    // 65536 shorts = 128 KB

    const int tid  = threadIdx.x;
    const int lane = tid & 63;
    const int wv   = tid >> 6;          // wave 0..7
    const int wr   = wv >> 2;           // 0..1 -> M offset wr*128
    const int wc   = wv & 3;            // 0..3 -> N offset wc*64
    const int l15  = lane & 15;
    const int l16  = lane >> 4;
    const int lj   = lane >> 3;         // staging row-within-8
    const int ss8  = lane & 7;          // staging 16B-slot

    const int nh = blockIdx.x >> 7;            // N-half 0..1
    const int mg = blockIdx.x & 127;           // M-group 0..127
    const int gn = nh * 256;
    size_t gm = (size_t)mg * 1024;             // job 0 M-base

    const unsigned short* Ab = (const unsigned short*)Ap;
    const float*          Af = (const float*)Ap;

    // ---- gll stage of one half-tile (bf16 source), inverse-swizzled src ----
    auto stage = [&](const unsigned short* gbase, size_t grow0, int region,
                     int half, int kt) {
#pragma unroll
        for (int j = 0; j < 2; ++j) {
            const int r = half * 128 + j * 64 + wv * 8 + lj;
            const unsigned short* src =
                gbase + (grow0 + r) * 512 + kt * 64 + ((ss8 ^ (r & 7)) * 8);
            unsigned short* dst = &lds[region + half * 8192 + j * 4096 + wv * 512];
            __builtin_amdgcn_global_load_lds((gvoid_t*)src, (lvoid_t*)dst, 16, 0, 0);
        }
    };
    // ---- f32-A reg staging: issue loads / cvt+swizzled ds_write ----
    auto loadAf = [&](float4* h, int half, int kt, size_t gmx) {
#pragma unroll
        for (int j = 0; j < 2; ++j) {
            const int r = half * 128 + j * 64 + wv * 8 + lj;
            const float* src = Af + (gmx + r) * 512 + kt * 64 + ss8 * 8;
            h[j * 2]     = *reinterpret_cast<const float4*>(src);
            h[j * 2 + 1] = *reinterpret_cast<const float4*>(src + 4);
        }
    };
    auto writeAf = [&](const float4* h, int region, int half) {
#pragma unroll
        for (int j = 0; j < 2; ++j) {
            const int r = half * 128 + j * 64 + wv * 8 + lj;
            float4 f0 = h[j * 2], f1 = h[j * 2 + 1];
            u16x8 o;
            o[0] = f2bf(f0.x); o[1] = f2bf(f0.y); o[2] = f2bf(f0.z); o[3] = f2bf(f0.w);
            o[4] = f2bf(f1.x); o[5] = f2bf(f1.y); o[6] = f2bf(f1.z); o[7] = f2bf(f1.w);
            *reinterpret_cast<u16x8*>(&lds[region + r * 64 + (ss8 ^ (r & 7)) * 8]) = o;
        }
    };

    f4_t  acc[8][4] = {};
    bf8_t bb[4][2];              // B frags of current K-tile
    bf8_t aq[2][2];              // A frags of current quadrant
    float4 afh0[4], afh1[4];     // in-flight f32 A halves (AF32)

    auto loadBall = [&](int region) {
#pragma unroll
        for (int n = 0; n < 4; ++n)
#pragma unroll
            for (int ks = 0; ks < 2; ++ks) {
                const int c  = wc * 64 + n * 16 + l15;
                const int sl = (ks * 4 + l16) ^ (l15 & 7);
                bb[n][ks] = *reinterpret_cast<const bf8_t*>(
                    (const char*)&lds[region] + c * 128 + sl * 16);
            }
    };
    auto loadAq = [&](int region, int q) {
#pragma unroll
        for (int m = 0; m < 2; ++m)
#pragma unroll
            for (int ks = 0; ks < 2; ++ks) {
                const int r  = wr * 128 + (q * 2 + m) * 16 + l15;
                const int sl = (ks * 4 + l16) ^ (l15 & 7);
                aq[m][ks] = *reinterpret_cast<const bf8_t*>(
                    (const char*)&lds[region] + r * 128 + sl * 16);
            }
    };
#define MFMA_Q(q)                                                              \
    _Pragma("unroll")                                                          \
    for (int m = 0; m < 2; ++m)                                                \
        _Pragma("unroll")                                                      \
        for (int n = 0; n < 4; ++n)                                            \
            _Pragma("unroll")                                                  \
            for (int ks = 0; ks < 2; ++ks)                                     \
                acc[(q) * 2 + m][n] = __builtin_amdgcn_mfma_f32_16x16x32_bf16( \
                    aq[m][ks], bb[n][ks], acc[(q) * 2 + m][n], 0, 0, 0);

    // ================= prologue (once): tile0 A+B, tile1 B =================
    if constexpr (AF32) {
        loadAf(afh0, 0, 0, gm); loadAf(afh1, 1, 0, gm);   // 8 loads
        stage(Bp, (size_t)gn, OFF_B0, 0, 0); stage(Bp, (size_t)gn, OFF_B0, 1, 0);
        stage(Bp, (size_t)gn, OFF_B1, 0, 1); stage(Bp, (size_t)gn, OFF_B1, 1, 1);
        VMC(8);                                           // A f32 landed
        writeAf(afh0, OFF_A0, 0); writeAf(afh1, OFF_A0, 1);
        VMC(4);                                           // B0 landed, B1 in flight
        LGKM0;
    } else {
        stage(Ab, gm, OFF_A0, 0, 0); stage(Ab, gm, OFF_A0, 1, 0);
        stage(Bp, (size_t)gn, OFF_B0, 0, 0); stage(Bp, (size_t)gn, OFF_B0, 1, 0);
        stage(Bp, (size_t)gn, OFF_B1, 0, 1); stage(Bp, (size_t)gn, OFF_B1, 1, 1);
        VMC(4);
    }
    __builtin_amdgcn_s_barrier();

    // ================= 4 jobs x (4 iters x 8 phases) =================
    for (int jb = 0; jb < 4; ++jb) {
        const size_t gmN = gm + 256;           // next job's M-base
        const bool   nx  = (jb < 3);

#pragma unroll
        for (int i = 0; i < 4; ++i) {
            const int    t1   = 2 * i + 1;
            const bool   last = (i == 3);
            const int    kt2  = last ? 0 : 2 * i + 2;   // compile-time (unrolled)
            const int    kt3  = last ? 1 : 2 * i + 3;
            const size_t g2   = last ? gmN : gm;
            const bool   st2  = (!last) || nx;

            // ---- p0: Btile+quad0 of tile 2i; stage A1h0(t1) ----
            loadBall(OFF_B0); loadAq(OFF_A0, 0);
            if constexpr (AF32) { loadAf(afh0, 0, t1, gm); } else { stage(Ab, gm, OFF_A1, 0, t1); }
            PH_PRE(); MFMA_Q(0); PH_POST();
            // ---- p1: quad1; stage A1h1(t1) ----
            loadAq(OFF_A0, 1);
            if constexpr (AF32) { loadAf(afh1, 1, t1, gm); } else { stage(Ab, gm, OFF_A1, 1, t1); }
            PH_PRE(); MFMA_Q(1); PH_POST();
            // ---- p2: quad2; stage B0h0(kt2); AF32: retire A1h0 ----
            loadAq(OFF_A0, 2);
            if (st2) stage(Bp, (size_t)gn, OFF_B0, 0, kt2);
            PH_PRE(); MFMA_Q(2);
            __builtin_amdgcn_s_setprio(0); __builtin_amdgcn_sched_barrier(0);
            if constexpr (AF32) {
                if (st2) { VMC(6); } else { VMC(4); }
                writeAf(afh0, OFF_A1, 0);
            }
            __builtin_amdgcn_s_barrier();
            // ---- p3: quad3; stage B0h1(kt2); vmcnt; AF32: retire A1h1 ----
            loadAq(OFF_A0, 3);
            if (st2) stage(Bp, (size_t)gn, OFF_B0, 1, kt2);
            PH_PRE(); MFMA_Q(3);
            __builtin_amdgcn_s_setprio(0); __builtin_amdgcn_sched_barrier(0);
            if constexpr (AF32) {
                if (st2) { VMC(4); } else { VMC(0); }
                writeAf(afh1, OFF_A1, 1);
                LGKM0;
            } else {
                if (st2) { VMC(4); } else { VMC(0); }
            }
            __builtin_amdgcn_s_barrier();

            // ---- p4: Btile+quad0 of tile 2i+1; stage A0h0(kt2@g2) ----
            loadBall(OFF_B1); loadAq(OFF_A1, 0);
            if (st2) { if constexpr (AF32) { loadAf(afh0, 0, kt2, g2); } else { stage(Ab, g2, OFF_A0, 0, kt2); } }
            PH_PRE(); MFMA_Q(0); PH_POST();
            // ---- p5: quad1; stage A0h1(kt2@g2) ----
            loadAq(OFF_A1, 1);
            if (st2) { if constexpr (AF32) { loadAf(afh1, 1, kt2, g2); } else { stage(Ab, g2, OFF_A0, 1, kt2); } }
            PH_PRE(); MFMA_Q(1); PH_POST();
            // ---- p6: quad2; stage B1h0(kt3); AF32: retire A0h0 ----
            loadAq(OFF_A1, 2);
            if (st2) stage(Bp, (size_t)gn, OFF_B1, 0, kt3);
            PH_PRE(); MFMA_Q(2);
            __builtin_amdgcn_s_setprio(0); __builtin_amdgcn_sched_barrier(0);
            if constexpr (AF32) { if (st2) { VMC(6); writeAf(afh0, OFF_A0, 0); } }
            __builtin_amdgcn_s_barrier();
            // ---- p7: quad3; stage B1h1(kt3); vmcnt; AF32: retire A0h1 ----
            loadAq(OFF_A1, 3);
            if (st2) stage(Bp, (size_t)gn, OFF_B1, 1, kt3);
            PH_PRE(); MFMA_Q(3);
            __builtin_amdgcn_s_setprio(0); __builtin_amdgcn_sched_barrier(0);
            if (st2) {
                VMC(4);
                if constexpr (AF32) { writeAf(afh1, OFF_A0, 1); LGKM0; }
            }
            __builtin_amdgcn_s_barrier();
        }

        // ---- job epilogue: write C for gm, reset acc (stores retire under
        //      next job's first phases; next vmcnt drains them once/job) ----
        const int crow0 = l16 * 4;
#pragma unroll
        for (int m = 0; m < 8; ++m)
#pragma unroll
            for (int n = 0; n < 4; ++n) {
                const size_t row0 = gm + (size_t)(wr * 128 + m * 16 + crow0);
                const int    col  = gn + wc * 64 + n * 16 + l15;
#pragma unroll
                for (int r = 0; r < 4; ++r)
                    C[(row0 + r) * 512 + col] = f2bf(acc[m][n][r]);
                acc[m][n] = (f4_t){0.f, 0.f, 0.f, 0.f};
            }
        gm = gmN;
    }
#undef MFMA_Q
}

// ------------- chunk-parallel scan, pass 1: per-chunk (A,B) summaries -------
__global__ __launch_bounds__(256)
void k_scan_p1(const unsigned short* __restrict__ q,
               const float* __restrict__ w_hh,
               const float* __restrict__ b_ih,
               float* __restrict__ Asum,
               float* __restrict__ Bsum) {
    const int g = (blockIdx.x & 63) * 256 + threadIdx.x;
    const int c = blockIdx.x >> 6;
    const float w  = w_hh[g & 511];
    const float bs = b_ih[g & 511];
    const unsigned short* p = q + (size_t)c * CLEN * S_STRIDE + g;

    float A = 0.f, Bv = 0.f;
    float s0[8], s1[8];
#pragma unroll
    for (int j = 0; j < 8; ++j) s0[j] = bf2f(p[(size_t)j * S_STRIDE]);
#pragma unroll
    for (int j = 0; j < 8; ++j) s1[j] = bf2f(p[(size_t)(8 + j) * S_STRIDE]);

    for (int j0 = 0; j0 < CLEN; j0 += 16) {
#pragma unroll
        for (int j = 0; j < 8; ++j) {
            float qv = s0[j] + bs;
            A  = fmaxf(fmaf(w, A, qv), 0.f);
            Bv = fmaf(w, Bv, qv);
        }
        if (j0 + 16 < CLEN) {
#pragma unroll
            for (int j = 0; j < 8; ++j) s0[j] = bf2f(p[(size_t)(j0 + 16 + j) * S_STRIDE]);
        }
#pragma unroll
        for (int j = 0; j < 8; ++j) {
            float qv = s1[j] + bs;
            A  = fmaxf(fmaf(w, A, qv), 0.f);
            Bv = fmaf(w, Bv, qv);
        }
        if (j0 + 24 < CLEN) {
#pragma unroll
            for (int j = 0; j < 8; ++j) s1[j] = bf2f(p[(size_t)(j0 + 24 + j) * S_STRIDE]);
        }
    }
    Asum[(size_t)c * NCHAIN + g] = A;
    Bsum[(size_t)c * NCHAIN + g] = Bv;
}

// ------------- pass 2: per-block stitch + exact replay ----------------------
template <int MODE>
__global__ __launch_bounds__(256)
void k_scan_p2(const unsigned short* __restrict__ q,
               const float* __restrict__ w_hh,
               const float* __restrict__ b_ih,
               const float* __restrict__ Asum,
               const float* __restrict__ Bsum,
               float* __restrict__ of32,
               unsigned short* __restrict__ ob16,
               float* __restrict__ hT) {
    const int g = (blockIdx.x & 63) * 256 + threadIdx.x;
    const int c = blockIdx.x >> 6;
    const float w  = w_hh[g & 511];
    const float bs = b_ih[g & 511];

    float cw = w;
#pragma unroll
    for (int i = 0; i < 7; ++i) cw *= cw;      // w^128
    float h = 0.f;
    for (int cc = 0; cc < c; ++cc)
        h = fmaxf(Asum[(size_t)cc * NCHAIN + g], fmaf(cw, h, Bsum[(size_t)cc * NCHAIN + g]));

    const size_t base = (size_t)c * CLEN * S_STRIDE + g;
    const unsigned short* p = q + base;

    float s0[8], s1[8];
#pragma unroll
    for (int j = 0; j < 8; ++j) s0[j] = bf2f(p[(size_t)j * S_STRIDE]);
#pragma unroll
    for (int j = 0; j < 8; ++j) s1[j] = bf2f(p[(size_t)(8 + j) * S_STRIDE]);

    for (int j0 = 0; j0 < CLEN; j0 += 16) {
#pragma unroll
        for (int j = 0; j < 8; ++j) {
            h = fmaxf(fmaf(w, h, s0[j] + bs), 0.f);
            const size_t idx = base + (size_t)(j0 + j) * S_STRIDE;
            if (MODE == 0) of32[idx] = h; else ob16[idx] = f2bf(h);
        }
        if (j0 + 16 < CLEN) {
#pragma unroll
            for (int j = 0; j < 8; ++j) s0[j] = bf2f(p[(size_t)(j0 + 16 + j) * S_STRIDE]);
        }
#pragma unroll
        for (int j = 0; j < 8; ++j) {
            h = fmaxf(fmaf(w, h, s1[j] + bs), 0.f);
            const size_t idx = base + (size_t)(j0 + 8 + j) * S_STRIDE;
            if (MODE == 0) of32[idx] = h; else ob16[idx] = f2bf(h);
        }
        if (j0 + 24 < CLEN) {
#pragma unroll
            for (int j = 0; j < 8; ++j) s1[j] = bf2f(p[(size_t)(j0 + 24 + j) * S_STRIDE]);
        }
    }
    if (c == NCH - 1) hT[g] = h;
}

extern "C" void kernel_launch(void* const* d_in, const int* in_sizes, int n_in,
                              void* d_out, int out_size, void* d_ws, size_t ws_size,
                              hipStream_t stream) {
    const float* x    = (const float*)d_in[0];   // (4096,32,512)
    const float* W_ih = (const float*)d_in[1];   // (2,512,512)
    const float* w_hh = (const float*)d_in[2];   // (2,512)
    const float* b_ih = (const float*)d_in[3];   // (2,512)

    // 128 KB dynamic LDS opt-in (idempotent; outside stream ops)
    hipFuncSetAttribute(reinterpret_cast<const void*>(&k_gemm8p<1>),
                        hipFuncAttributeMaxDynamicSharedMemorySize, GLDS_B);
    hipFuncSetAttribute(reinterpret_cast<const void*>(&k_gemm8p<0>),
                        hipFuncAttributeMaxDynamicSharedMemorySize, GLDS_B);

    // ---- workspace layout (~139 MB) ----
    unsigned short* proj2 = (unsigned short*)d_ws;                // 134 MB
    unsigned short* Wb    = proj2 + OUT_ELEMS;                    // 1 MB
    float* Asum = (float*)(Wb + 2 * 512 * 512);                   // 2 MB
    float* Bsum = Asum + (size_t)NCH * NCHAIN;                    // 2 MB

    // ---- d_out staging: proj1 (bf16) lower half, ys1 (bf16) upper half ----
    unsigned short* proj1 = (unsigned short*)d_out;
    unsigned short* ys1   = proj1 + OUT_ELEMS;
    float* out = (float*)d_out;
    float* hT  = out + OUT_ELEMS;                                 // h_n (2,32,512)

    const int sgrid = 64 * NCH;             // 2048 blocks for scan passes

    // 1. W -> bf16
    k_cvt<<<524288 / 8 / 256, 256, 0, stream>>>(W_ih, Wb);
    // 2. layer-0 GEMM (A = x f32, fused cvt) -> proj1
    k_gemm8p<1><<<256, 512, GLDS_B, stream>>>(x, Wb, proj1);
    // 3-4. layer-0 chunked scan -> ys1 (bf16) + hT0
    k_scan_p1<<<sgrid, 256, 0, stream>>>(proj1, w_hh, b_ih, Asum, Bsum);
    k_scan_p2<1><<<sgrid, 256, 0, stream>>>(proj1, w_hh, b_ih, Asum, Bsum,
                                            nullptr, ys1, hT);
    // 5. layer-1 GEMM (A = ys1 bf16) -> proj2 (ws)
    k_gemm8p<0><<<256, 512, GLDS_B, stream>>>(ys1, Wb + 512 * 512, proj2);
    // 6-7. layer-1 chunked scan -> final out (f32, overwrites proj1/ys1) + hT1
    k_scan_p1<<<sgrid, 256, 0, stream>>>(proj2, w_hh + DIM, b_ih + DIM, Asum, Bsum);
    k_scan_p2<0><<<sgrid, 256, 0, stream>>>(proj2, w_hh + DIM, b_ih + DIM, Asum, Bsum,
                                            out, nullptr, hT + NCHAIN);
}

// Round 13
// 404.089 us; speedup vs baseline: 1.5555x; 1.5536x over previous
//
#include <hip/hip_runtime.h>

// Problem constants (fixed by the reference)
#define T_SEQ   4096
#define BATCH   32
#define DIM     512
#define MROWS   (T_SEQ * BATCH)          // 131072 GEMM rows
#define S_STRIDE (BATCH * DIM)           // 16384 elements per time step
#define OUT_ELEMS ((size_t)T_SEQ * BATCH * DIM)   // 67108864
#define NCH     32                        // T-chunks for parallel scan
#define CLEN    (T_SEQ / NCH)             // 128 steps per chunk
#define NCHAIN  (BATCH * DIM)             // 16384 independent chains

// 8-phase GEMM geometry: BM=BN=256, BK=64, 8 waves (2Mx4N), LDS 128 KB
#define GNWG    ((MROWS / 256) * (DIM / 256))   // 1024 blocks
#define OFF_A0  0          // shorts; each region 16384 shorts = 32 KB
#define OFF_A1  16384
#define OFF_B0  32768
#define OFF_B1  49152
#define GLDS_B  131072

typedef __bf16 bf8_t __attribute__((ext_vector_type(8)));
typedef float  f4_t  __attribute__((ext_vector_type(4)));
typedef unsigned short u16x8 __attribute__((ext_vector_type(8)));
typedef __attribute__((address_space(1))) void gvoid_t;
typedef __attribute__((address_space(3))) void lvoid_t;

__device__ __forceinline__ unsigned short f2bf(float f) {
    unsigned int u = __float_as_uint(f);
    u += 0x7FFFu + ((u >> 16) & 1u);     // round-to-nearest-even
    return (unsigned short)(u >> 16);
}
__device__ __forceinline__ float bf2f(unsigned short b) {
    return __uint_as_float(((unsigned int)b) << 16);
}

#define VMC(n)  asm volatile("s_waitcnt vmcnt(" #n ")" ::: "memory")
#define LGKM0   asm volatile("s_waitcnt lgkmcnt(0)" ::: "memory")
#define PH_PRE()  do { __builtin_amdgcn_s_barrier(); LGKM0;                    \
                       __builtin_amdgcn_sched_barrier(0);                      \
                       __builtin_amdgcn_s_setprio(1); } while (0)
#define PH_POST() do { __builtin_amdgcn_s_setprio(0);                          \
                       __builtin_amdgcn_sched_barrier(0);                      \
                       __builtin_amdgcn_s_barrier(); } while (0)

// ---------------- f32 -> bf16 convert (weights only) -----------------
__global__ __launch_bounds__(256) void k_cvt(const float* __restrict__ in,
                                             unsigned short* __restrict__ out) {
    size_t i = ((size_t)blockIdx.x * 256 + threadIdx.x) * 8;
    float4 a = *reinterpret_cast<const float4*>(in + i);
    float4 b = *reinterpret_cast<const float4*>(in + i + 4);
    u16x8 o;
    o[0] = f2bf(a.x); o[1] = f2bf(a.y); o[2] = f2bf(a.z); o[3] = f2bf(a.w);
    o[4] = f2bf(b.x); o[5] = f2bf(b.y); o[6] = f2bf(b.z); o[7] = f2bf(b.w);
    *reinterpret_cast<u16x8*>(out + i) = o;
}

// ---------------- 8-phase 256x256 bf16 GEMM  C = A * B^T -------------
// K=512 -> 8 K-tiles (BK=64), 4 iterations x 8 phases, 2 LDS buffers.
// XOR swizzle: 16B slot s of row r stored at s^(r&7)  (T2; 2-way max).
// gll sources pre-inverse-swizzled (rule #21). vmcnt(4) at p3/p7 only (T4).
// AF32=1: A f32; loads issued in the A-stage slots, cvt+swizzled ds_write
// after that phase's MFMA (T14), drained by the same vmcnt points.
template <int AF32>
__global__ __launch_bounds__(512, 2)
void k_gemm8(const void* __restrict__ Ap,
             const unsigned short* __restrict__ Bp,
             unsigned short* __restrict__ C) {
    extern __shared__ unsigned short lds[];    // 65536 shorts = 128 KB

    const int tid  = threadIdx.x;
    const int lane = tid & 63;
    const int wv   = tid >> 6;          // wave 0..7
    const int wr   = wv >> 2;           // 0..1 -> M offset wr*128
    const int wc   = wv & 3;            // 0..3 -> N offset wc*64
    const int l15  = lane & 15;
    const int l16  = lane >> 4;
    const int lj   = lane >> 3;         // staging row-within-8
    const int ss8  = lane & 7;          // staging 16B-slot

    // bijective XCD swizzle (GNWG % 8 == 0); s,s^1 share the A-panel
    const int sid = (blockIdx.x & 7) * (GNWG / 8) + (blockIdx.x >> 3);
    const size_t gm = (size_t)(sid >> 1) * 256;
    const int    gn = (sid & 1) * 256;

    const unsigned short* Ab = (const unsigned short*)Ap;
    const float*          Af = (const float*)Ap;

    // ---- gll stage of one half-tile (bf16 source), inverse-swizzled src ----
    auto stage = [&](const unsigned short* gbase, size_t grow0, int region,
                     int half, int kt) {
#pragma unroll
        for (int j = 0; j < 2; ++j) {
            const int r = half * 128 + j * 64 + wv * 8 + lj;
            const unsigned short* src =
                gbase + (grow0 + r) * 512 + kt * 64 + ((ss8 ^ (r & 7)) * 8);
            unsigned short* dst = &lds[region + half * 8192 + j * 4096 + wv * 512];
            __builtin_amdgcn_global_load_lds((gvoid_t*)src, (lvoid_t*)dst, 16, 0, 0);
        }
    };
    // ---- f32-A reg staging: issue loads / cvt+swizzled ds_write ----
    auto loadAf = [&](float4* h, int half, int kt) {
#pragma unroll
        for (int j = 0; j < 2; ++j) {
            const int r = half * 128 + j * 64 + wv * 8 + lj;
            const float* src = Af + (gm + r) * 512 + kt * 64 + ss8 * 8;
            h[j * 2]     = *reinterpret_cast<const float4*>(src);
            h[j * 2 + 1] = *reinterpret_cast<const float4*>(src + 4);
        }
    };
    auto writeAf = [&](const float4* h, int region, int half) {
#pragma unroll
        for (int j = 0; j < 2; ++j) {
            const int r = half * 128 + j * 64 + wv * 8 + lj;
            float4 f0 = h[j * 2], f1 = h[j * 2 + 1];
            u16x8 o;
            o[0] = f2bf(f0.x); o[1] = f2bf(f0.y); o[2] = f2bf(f0.z); o[3] = f2bf(f0.w);
            o[4] = f2bf(f1.x); o[5] = f2bf(f1.y); o[6] = f2bf(f1.z); o[7] = f2bf(f1.w);
            *reinterpret_cast<u16x8*>(&lds[region + r * 64 + (ss8 ^ (r & 7)) * 8]) = o;
        }
    };

    f4_t  acc[8][4] = {};
    bf8_t bb[4][2];              // B frags of current K-tile
    bf8_t aq[2][2];              // A frags of current quadrant
    float4 afh0[4], afh1[4];     // in-flight f32 A halves (AF32)

    auto loadBall = [&](int region) {
#pragma unroll
        for (int n = 0; n < 4; ++n)
#pragma unroll
            for (int ks = 0; ks < 2; ++ks) {
                const int c  = wc * 64 + n * 16 + l15;
                const int sl = (ks * 4 + l16) ^ (l15 & 7);
                bb[n][ks] = *reinterpret_cast<const bf8_t*>(
                    (const char*)&lds[region] + c * 128 + sl * 16);
            }
    };
    auto loadAq = [&](int region, int q) {
#pragma unroll
        for (int m = 0; m < 2; ++m)
#pragma unroll
            for (int ks = 0; ks < 2; ++ks) {
                const int r  = wr * 128 + (q * 2 + m) * 16 + l15;
                const int sl = (ks * 4 + l16) ^ (l15 & 7);
                aq[m][ks] = *reinterpret_cast<const bf8_t*>(
                    (const char*)&lds[region] + r * 128 + sl * 16);
            }
    };
#define MFMA_Q(q)                                                              \
    _Pragma("unroll")                                                          \
    for (int m = 0; m < 2; ++m)                                                \
        _Pragma("unroll")                                                      \
        for (int n = 0; n < 4; ++n)                                            \
            _Pragma("unroll")                                                  \
            for (int ks = 0; ks < 2; ++ks)                                     \
                acc[(q) * 2 + m][n] = __builtin_amdgcn_mfma_f32_16x16x32_bf16( \
                    aq[m][ks], bb[n][ks], acc[(q) * 2 + m][n], 0, 0, 0);

    // ================= prologue: tile0 A+B, tile1 B =================
    if constexpr (AF32) {
        loadAf(afh0, 0, 0); loadAf(afh1, 1, 0);          // 8 loads
        stage(Bp, (size_t)gn, OFF_B0, 0, 0); stage(Bp, (size_t)gn, OFF_B0, 1, 0);
        stage(Bp, (size_t)gn, OFF_B1, 0, 1); stage(Bp, (size_t)gn, OFF_B1, 1, 1);
        VMC(8);                                           // A f32 landed
        writeAf(afh0, OFF_A0, 0); writeAf(afh1, OFF_A0, 1);
        VMC(4);                                           // B0 landed, B1 in flight
        LGKM0;
    } else {
        stage(Ab, gm, OFF_A0, 0, 0); stage(Ab, gm, OFF_A0, 1, 0);
        stage(Bp, (size_t)gn, OFF_B0, 0, 0); stage(Bp, (size_t)gn, OFF_B0, 1, 0);
        stage(Bp, (size_t)gn, OFF_B1, 0, 1); stage(Bp, (size_t)gn, OFF_B1, 1, 1);
        VMC(4);
    }
    __builtin_amdgcn_s_barrier();

    // ================= main loop: 4 iters x 8 phases =================
#pragma unroll
    for (int i = 0; i < 4; ++i) {
        const int t1 = 2 * i + 1, t2 = 2 * i + 2, t3 = 2 * i + 3;
        const bool st2 = (i < 3);      // stage tiles t2/t3 only while they exist

        // ---- p0: Btile read + A-quad0 of tile 2i; stage A1h0(t1) ----
        loadBall(OFF_B0); loadAq(OFF_A0, 0);
        if constexpr (AF32) { loadAf(afh0, 0, t1); } else { stage(Ab, gm, OFF_A1, 0, t1); }
        PH_PRE(); MFMA_Q(0); PH_POST();
        // ---- p1: quad1; stage A1h1(t1) ----
        loadAq(OFF_A0, 1);
        if constexpr (AF32) { loadAf(afh1, 1, t1); } else { stage(Ab, gm, OFF_A1, 1, t1); }
        PH_PRE(); MFMA_Q(1); PH_POST();
        // ---- p2: quad2; stage B0h0(t2); AF32: retire A1h0 ----
        loadAq(OFF_A0, 2);
        if (st2) stage(Bp, (size_t)gn, OFF_B0, 0, t2);
        PH_PRE(); MFMA_Q(2);
        __builtin_amdgcn_s_setprio(0); __builtin_amdgcn_sched_barrier(0);
        if constexpr (AF32) {
            if (st2) { VMC(6); } else { VMC(4); }
            writeAf(afh0, OFF_A1, 0);
        }
        __builtin_amdgcn_s_barrier();
        // ---- p3: quad3; stage B0h1(t2); vmcnt; AF32: retire A1h1 ----
        loadAq(OFF_A0, 3);
        if (st2) stage(Bp, (size_t)gn, OFF_B0, 1, t2);
        PH_PRE(); MFMA_Q(3);
        __builtin_amdgcn_s_setprio(0); __builtin_amdgcn_sched_barrier(0);
        if constexpr (AF32) {
            if (st2) { VMC(4); } else { VMC(0); }
            writeAf(afh1, OFF_A1, 1);
            LGKM0;
        } else {
            if (st2) { VMC(4); } else { VMC(0); }
        }
        __builtin_amdgcn_s_barrier();

        // ---- p4: Btile read + quad0 of tile 2i+1; stage A0h0(t2) ----
        loadBall(OFF_B1); loadAq(OFF_A1, 0);
        if (st2) { if constexpr (AF32) { loadAf(afh0, 0, t2); } else { stage(Ab, gm, OFF_A0, 0, t2); } }
        PH_PRE(); MFMA_Q(0); PH_POST();
        // ---- p5: quad1; stage A0h1(t2) ----
        loadAq(OFF_A1, 1);
        if (st2) { if constexpr (AF32) { loadAf(afh1, 1, t2); } else { stage(Ab, gm, OFF_A0, 1, t2); } }
        PH_PRE(); MFMA_Q(1); PH_POST();
        // ---- p6: quad2; stage B1h0(t3); AF32: retire A0h0 ----
        loadAq(OFF_A1, 2);
        if (st2) stage(Bp, (size_t)gn, OFF_B1, 0, t3);
        PH_PRE(); MFMA_Q(2);
        __builtin_amdgcn_s_setprio(0); __builtin_amdgcn_sched_barrier(0);
        if constexpr (AF32) { if (st2) { VMC(6); writeAf(afh0, OFF_A0, 0); } }
        __builtin_amdgcn_s_barrier();
        // ---- p7: quad3; stage B1h1(t3); vmcnt; AF32: retire A0h1 ----
        loadAq(OFF_A1, 3);
        if (st2) stage(Bp, (size_t)gn, OFF_B1, 1, t3);
        PH_PRE(); MFMA_Q(3);
        __builtin_amdgcn_s_setprio(0); __builtin_amdgcn_sched_barrier(0);
        if (st2) {
            VMC(4);
            if constexpr (AF32) { writeAf(afh1, OFF_A0, 1); LGKM0; }
        }
        __builtin_amdgcn_s_barrier();
    }
#undef MFMA_Q

    // ================= epilogue: C/D col=lane&15, row=(lane>>4)*4+reg ====
    const int crow0 = l16 * 4;
#pragma unroll
    for (int m = 0; m < 8; ++m)
#pragma unroll
        for (int n = 0; n < 4; ++n) {
            const size_t row0 = gm + (size_t)(wr * 128 + m * 16 + crow0);
            const int    col  = gn + wc * 64 + n * 16 + l15;
#pragma unroll
            for (int r = 0; r < 4; ++r)
                C[(row0 + r) * 512 + col] = f2bf(acc[m][n][r]);
        }
}

// ------------- chunk-parallel scan, pass 1: per-chunk (A,B) summaries -------
__global__ __launch_bounds__(256)
void k_scan_p1(const unsigned short* __restrict__ q,
               const float* __restrict__ w_hh,
               const float* __restrict__ b_ih,
               float* __restrict__ Asum,
               float* __restrict__ Bsum) {
    const int g = (blockIdx.x & 63) * 256 + threadIdx.x;
    const int c = blockIdx.x >> 6;
    const float w  = w_hh[g & 511];
    const float bs = b_ih[g & 511];
    const unsigned short* p = q + (size_t)c * CLEN * S_STRIDE + g;

    float A = 0.f, Bv = 0.f;
    float s0[8], s1[8];
#pragma unroll
    for (int j = 0; j < 8; ++j) s0[j] = bf2f(p[(size_t)j * S_STRIDE]);
#pragma unroll
    for (int j = 0; j < 8; ++j) s1[j] = bf2f(p[(size_t)(8 + j) * S_STRIDE]);

    for (int j0 = 0; j0 < CLEN; j0 += 16) {
#pragma unroll
        for (int j = 0; j < 8; ++j) {
            float qv = s0[j] + bs;
            A  = fmaxf(fmaf(w, A, qv), 0.f);
            Bv = fmaf(w, Bv, qv);
        }
        if (j0 + 16 < CLEN) {
#pragma unroll
            for (int j = 0; j < 8; ++j) s0[j] = bf2f(p[(size_t)(j0 + 16 + j) * S_STRIDE]);
        }
#pragma unroll
        for (int j = 0; j < 8; ++j) {
            float qv = s1[j] + bs;
            A  = fmaxf(fmaf(w, A, qv), 0.f);
            Bv = fmaf(w, Bv, qv);
        }
        if (j0 + 24 < CLEN) {
#pragma unroll
            for (int j = 0; j < 8; ++j) s1[j] = bf2f(p[(size_t)(j0 + 24 + j) * S_STRIDE]);
        }
    }
    Asum[(size_t)c * NCHAIN + g] = A;
    Bsum[(size_t)c * NCHAIN + g] = Bv;
}

// ------------- pass 2: per-block stitch + exact replay ----------------------
template <int MODE>
__global__ __launch_bounds__(256)
void k_scan_p2(const unsigned short* __restrict__ q,
               const float* __restrict__ w_hh,
               const float* __restrict__ b_ih,
               const float* __restrict__ Asum,
               const float* __restrict__ Bsum,
               float* __restrict__ of32,
               unsigned short* __restrict__ ob16,
               float* __restrict__ hT) {
    const int g = (blockIdx.x & 63) * 256 + threadIdx.x;
    const int c = blockIdx.x >> 6;
    const float w  = w_hh[g & 511];
    const float bs = b_ih[g & 511];

    float cw = w;
#pragma unroll
    for (int i = 0; i < 7; ++i) cw *= cw;      // w^128
    float h = 0.f;
    for (int cc = 0; cc < c; ++cc)
        h = fmaxf(Asum[(size_t)cc * NCHAIN + g], fmaf(cw, h, Bsum[(size_t)cc * NCHAIN + g]));

    const size_t base = (size_t)c * CLEN * S_STRIDE + g;
    const unsigned short* p = q + base;

    float s0[8], s1[8];
#pragma unroll
    for (int j = 0; j < 8; ++j) s0[j] = bf2f(p[(size_t)j * S_STRIDE]);
#pragma unroll
    for (int j = 0; j < 8; ++j) s1[j] = bf2f(p[(size_t)(8 + j) * S_STRIDE]);

    for (int j0 = 0; j0 < CLEN; j0 += 16) {
#pragma unroll
        for (int j = 0; j < 8; ++j) {
            h = fmaxf(fmaf(w, h, s0[j] + bs), 0.f);
            const size_t idx = base + (size_t)(j0 + j) * S_STRIDE;
            if (MODE == 0) of32[idx] = h; else ob16[idx] = f2bf(h);
        }
        if (j0 + 16 < CLEN) {
#pragma unroll
            for (int j = 0; j < 8; ++j) s0[j] = bf2f(p[(size_t)(j0 + 16 + j) * S_STRIDE]);
        }
#pragma unroll
        for (int j = 0; j < 8; ++j) {
            h = fmaxf(fmaf(w, h, s1[j] + bs), 0.f);
            const size_t idx = base + (size_t)(j0 + 8 + j) * S_STRIDE;
            if (MODE == 0) of32[idx] = h; else ob16[idx] = f2bf(h);
        }
        if (j0 + 24 < CLEN) {
#pragma unroll
            for (int j = 0; j < 8; ++j) s1[j] = bf2f(p[(size_t)(j0 + 24 + j) * S_STRIDE]);
        }
    }
    if (c == NCH - 1) hT[g] = h;
}

extern "C" void kernel_launch(void* const* d_in, const int* in_sizes, int n_in,
                              void* d_out, int out_size, void* d_ws, size_t ws_size,
                              hipStream_t stream) {
    const float* x    = (const float*)d_in[0];   // (4096,32,512)
    const float* W_ih = (const float*)d_in[1];   // (2,512,512)
    const float* w_hh = (const float*)d_in[2];   // (2,512)
    const float* b_ih = (const float*)d_in[3];   // (2,512)

    // 128 KB dynamic LDS opt-in (idempotent; outside stream ops)
    hipFuncSetAttribute(reinterpret_cast<const void*>(&k_gemm8<1>),
                        hipFuncAttributeMaxDynamicSharedMemorySize, GLDS_B);
    hipFuncSetAttribute(reinterpret_cast<const void*>(&k_gemm8<0>),
                        hipFuncAttributeMaxDynamicSharedMemorySize, GLDS_B);

    // ---- workspace layout (~139 MB) ----
    unsigned short* proj2 = (unsigned short*)d_ws;                // 134 MB
    unsigned short* Wb    = proj2 + OUT_ELEMS;                    // 1 MB
    float* Asum = (float*)(Wb + 2 * 512 * 512);                   // 2 MB
    float* Bsum = Asum + (size_t)NCH * NCHAIN;                    // 2 MB

    // ---- d_out staging: proj1 (bf16) lower half, ys1 (bf16) upper half ----
    unsigned short* proj1 = (unsigned short*)d_out;
    unsigned short* ys1   = proj1 + OUT_ELEMS;
    float* out = (float*)d_out;
    float* hT  = out + OUT_ELEMS;                                 // h_n (2,32,512)

    const int sgrid = 64 * NCH;             // 2048 blocks for scan passes

    // 1. W -> bf16
    k_cvt<<<524288 / 8 / 256, 256, 0, stream>>>(W_ih, Wb);
    // 2. layer-0 GEMM (A = x f32, fused cvt) -> proj1
    k_gemm8<1><<<GNWG, 512, GLDS_B, stream>>>(x, Wb, proj1);
    // 3-4. layer-0 chunked scan -> ys1 (bf16) + hT0
    k_scan_p1<<<sgrid, 256, 0, stream>>>(proj1, w_hh, b_ih, Asum, Bsum);
    k_scan_p2<1><<<sgrid, 256, 0, stream>>>(proj1, w_hh, b_ih, Asum, Bsum,
                                            nullptr, ys1, hT);
    // 5. layer-1 GEMM (A = ys1 bf16) -> proj2 (ws)
    k_gemm8<0><<<GNWG, 512, GLDS_B, stream>>>(ys1, Wb + 512 * 512, proj2);
    // 6-7. layer-1 chunked scan -> final out (f32, overwrites proj1/ys1) + hT1
    k_scan_p1<<<sgrid, 256, 0, stream>>>(proj2, w_hh + DIM, b_ih + DIM, Asum, Bsum);
    k_scan_p2<0><<<sgrid, 256, 0, stream>>>(proj2, w_hh + DIM, b_ih + DIM, Asum, Bsum,
                                            out, nullptr, hT + NCHAIN);
}